// Round 2
// baseline (5994.100 us; speedup 1.0000x reference)
//
#include <hip/hip_runtime.h>

#define BSZ  5
#define PROJ 1000
#define DET  513
#define IMG  362
#define NPIX (IMG * IMG)          // 131044
#define SINO (PROJ * DET)         // 513000
#define NNZ  20000000

// Fast path workspace layout:
//   sino_t : [SINO][8] floats  (batch 0..4 in slots 0..4, pad 5..7)   16.42 MB
//   acc    : [NCOPY][NPIX][8] floats (slots 0..4 = batches, 5 = sens) 4.19 MB/copy
#define SINO_T_FLOATS ((size_t)SINO * 8)
#define COPY_FLOATS   ((size_t)NPIX * 8)

__device__ __forceinline__ int xcc_id() {
    int x;
    asm volatile("s_getreg_b32 %0, hwreg(HW_REG_XCC_ID)" : "=s"(x));
    return x & 7;
}

__global__ void sino_transpose_kernel(const float* __restrict__ sino,
                                      float* __restrict__ sino_t) {
    const int c = blockIdx.x * blockDim.x + threadIdx.x;
    if (c < SINO) {
        float4 lo, hi;
        lo.x = sino[0 * (size_t)SINO + c];
        lo.y = sino[1 * (size_t)SINO + c];
        lo.z = sino[2 * (size_t)SINO + c];
        lo.w = sino[3 * (size_t)SINO + c];
        hi.x = sino[4 * (size_t)SINO + c];
        hi.y = 0.f; hi.z = 0.f; hi.w = 0.f;
        float4* dst = (float4*)(sino_t + (size_t)c * 8);
        dst[0] = lo;
        dst[1] = hi;
    }
}

template <int NCOPY, bool LOCAL>
__global__ void bp_scatter_kernel(const float* __restrict__ sino_t,
                                  const float* __restrict__ vals,
                                  const int*   __restrict__ rows,
                                  const int*   __restrict__ cols,
                                  float* __restrict__ acc) {
    const int xcd = LOCAL ? (xcc_id() & (NCOPY - 1)) : 0;
    float* myacc = acc + (size_t)xcd * COPY_FLOATS;

    const long long stride = (long long)gridDim.x * blockDim.x;
    for (long long i = (long long)blockIdx.x * blockDim.x + threadIdx.x;
         i < NNZ; i += stride) {
        const float v = vals[i];
        const int   r = rows[i];
        const int   c = cols[i];
        const float4 s0 = *(const float4*)(sino_t + (size_t)c * 8);
        const float  s4 = sino_t[(size_t)c * 8 + 4];
        float* base = myacc + (size_t)r * 8;
        if (LOCAL) {
            __hip_atomic_fetch_add(base + 0, v * s0.x, __ATOMIC_RELAXED, __HIP_MEMORY_SCOPE_WORKGROUP);
            __hip_atomic_fetch_add(base + 1, v * s0.y, __ATOMIC_RELAXED, __HIP_MEMORY_SCOPE_WORKGROUP);
            __hip_atomic_fetch_add(base + 2, v * s0.z, __ATOMIC_RELAXED, __HIP_MEMORY_SCOPE_WORKGROUP);
            __hip_atomic_fetch_add(base + 3, v * s0.w, __ATOMIC_RELAXED, __HIP_MEMORY_SCOPE_WORKGROUP);
            __hip_atomic_fetch_add(base + 4, v * s4,   __ATOMIC_RELAXED, __HIP_MEMORY_SCOPE_WORKGROUP);
            __hip_atomic_fetch_add(base + 5, v,        __ATOMIC_RELAXED, __HIP_MEMORY_SCOPE_WORKGROUP);
        } else {
            atomicAdd(base + 0, v * s0.x);
            atomicAdd(base + 1, v * s0.y);
            atomicAdd(base + 2, v * s0.z);
            atomicAdd(base + 3, v * s0.w);
            atomicAdd(base + 4, v * s4);
            atomicAdd(base + 5, v);
        }
    }
}

__global__ void bp_reduce_divide_kernel(const float* __restrict__ acc,
                                        float* __restrict__ out,
                                        int ncopies) {
    const int i = blockIdx.x * blockDim.x + threadIdx.x;
    if (i < BSZ * NPIX) {
        const int b = i / NPIX;
        const int p = i - b * NPIX;
        float num = 0.f, den = 0.f;
        for (int x = 0; x < ncopies; ++x) {
            const float* base = acc + (size_t)x * COPY_FLOATS + (size_t)p * 8;
            num += base[b];
            den += base[5];
        }
        out[i] = num / den;
    }
}

// ---- round-0 fallback (tiny workspace): planar acc + device-scope atomics ----
__global__ void bp_scatter_fb_kernel(const float* __restrict__ sino,
                                     const float* __restrict__ vals,
                                     const int*   __restrict__ rows,
                                     const int*   __restrict__ cols,
                                     float* __restrict__ acc) {
    const long long stride = (long long)gridDim.x * blockDim.x;
    for (long long i = (long long)blockIdx.x * blockDim.x + threadIdx.x;
         i < NNZ; i += stride) {
        const float v = vals[i];
        const int   r = rows[i];
        const int   c = cols[i];
        atomicAdd(acc + (size_t)BSZ * NPIX + r, v);
#pragma unroll
        for (int b = 0; b < BSZ; ++b)
            atomicAdd(acc + (size_t)b * NPIX + r, v * sino[(size_t)b * SINO + c]);
    }
}

__global__ void bp_divide_fb_kernel(const float* __restrict__ acc,
                                    float* __restrict__ out) {
    const int i = blockIdx.x * blockDim.x + threadIdx.x;
    if (i < BSZ * NPIX) {
        const int p = i % NPIX;
        out[i] = acc[i] / acc[(size_t)BSZ * NPIX + p];
    }
}

extern "C" void kernel_launch(void* const* d_in, const int* in_sizes, int n_in,
                              void* d_out, int out_size, void* d_ws, size_t ws_size,
                              hipStream_t stream) {
    const float* sino = (const float*)d_in[0];   // [BSZ, PROJ, DET, 1]
    const float* vals = (const float*)d_in[1];
    const int*   rows = (const int*)d_in[2];
    const int*   cols = (const int*)d_in[3];
    float* out = (float*)d_out;

    const int block = 256;
    const size_t need_fast = (SINO_T_FLOATS + 8 * COPY_FLOATS) * sizeof(float); // ~50 MB
    const size_t need_mid  = (SINO_T_FLOATS + 1 * COPY_FLOATS) * sizeof(float); // ~21 MB

    if (ws_size >= need_fast || ws_size >= need_mid) {
        float* sino_t = (float*)d_ws;
        float* acc = sino_t + SINO_T_FLOATS;
        const int ncopies = (ws_size >= need_fast) ? 8 : 1;

        hipMemsetAsync(acc, 0, (size_t)ncopies * COPY_FLOATS * sizeof(float), stream);
        sino_transpose_kernel<<<(SINO + block - 1) / block, block, 0, stream>>>(sino, sino_t);

        if (ncopies == 8)
            bp_scatter_kernel<8, true><<<2048, block, 0, stream>>>(sino_t, vals, rows, cols, acc);
        else
            bp_scatter_kernel<1, false><<<2048, block, 0, stream>>>(sino_t, vals, rows, cols, acc);

        const int n_out = BSZ * NPIX;
        bp_reduce_divide_kernel<<<(n_out + block - 1) / block, block, 0, stream>>>(acc, out, ncopies);
    } else {
        // minimal-workspace fallback
        float* acc = (float*)d_ws;  // (BSZ+1)*NPIX floats
        hipMemsetAsync(acc, 0, (size_t)(BSZ + 1) * NPIX * sizeof(float), stream);
        bp_scatter_fb_kernel<<<2048, block, 0, stream>>>(sino, vals, rows, cols, acc);
        const int n_out = BSZ * NPIX;
        bp_divide_fb_kernel<<<(n_out + block - 1) / block, block, 0, stream>>>(acc, out);
    }
}

// Round 3
// 1054.144 us; speedup vs baseline: 5.6862x; 5.6862x over previous
//
#include <hip/hip_runtime.h>

#define BSZ  5
#define PROJ 1000
#define DET  513
#define IMG  362
#define NPIX (IMG * IMG)          // 131044
#define SINO (PROJ * DET)         // 513000
#define NNZ  20000000

#define BIN_SHIFT 9
#define BIN_PX    512
#define NBINS     256             // ceil(NPIX / 512)
#define BPB       4               // blocks (= acc copies) per bin in accum
#define ACC_FLOATS ((size_t)NBINS * BIN_PX * 6)   // 786432 floats per copy

#define SINO_T_FLOATS ((size_t)SINO * 8)          // 4,104,000
#define REC_FLOATS    ((size_t)NNZ * 2)           // 40,000,000 (float2 records)

// ---------------- fast path kernels ----------------

__global__ void sino_transpose_kernel(const float* __restrict__ sino,
                                      float* __restrict__ sino_t) {
    const int c = blockIdx.x * blockDim.x + threadIdx.x;
    if (c < SINO) {
        float4 lo, hi;
        lo.x = sino[0 * (size_t)SINO + c];
        lo.y = sino[1 * (size_t)SINO + c];
        lo.z = sino[2 * (size_t)SINO + c];
        lo.w = sino[3 * (size_t)SINO + c];
        hi.x = sino[4 * (size_t)SINO + c];
        hi.y = 0.f; hi.z = 0.f; hi.w = 0.f;
        float4* dst = (float4*)(sino_t + (size_t)c * 8);
        dst[0] = lo;
        dst[1] = hi;
    }
}

__global__ void hist_kernel(const int* __restrict__ rows,
                            unsigned* __restrict__ hist) {
    __shared__ unsigned h[NBINS];
    h[threadIdx.x] = 0;
    __syncthreads();
    const long long stride = (long long)gridDim.x * blockDim.x;
    const long long n4 = NNZ / 4;
    for (long long i = (long long)blockIdx.x * blockDim.x + threadIdx.x;
         i < n4; i += stride) {
        const int4 r = ((const int4*)rows)[i];
        atomicAdd(&h[r.x >> BIN_SHIFT], 1u);
        atomicAdd(&h[r.y >> BIN_SHIFT], 1u);
        atomicAdd(&h[r.z >> BIN_SHIFT], 1u);
        atomicAdd(&h[r.w >> BIN_SHIFT], 1u);
    }
    __syncthreads();
    atomicAdd(&hist[threadIdx.x], h[threadIdx.x]);
}

__global__ void scan_kernel(const unsigned* __restrict__ hist,
                            unsigned* __restrict__ bin_start,
                            unsigned* __restrict__ cursor) {
    __shared__ unsigned s[NBINS];
    const int t = threadIdx.x;
    const unsigned my = hist[t];
    s[t] = my;
    __syncthreads();
    for (int off = 1; off < NBINS; off <<= 1) {
        unsigned v = (t >= off) ? s[t - off] : 0u;
        __syncthreads();
        s[t] += v;
        __syncthreads();
    }
    const unsigned excl = s[t] - my;
    bin_start[t] = excl;
    cursor[t] = excl;
    if (t == NBINS - 1) bin_start[NBINS] = (unsigned)NNZ;
}

__global__ void binscatter_kernel(const float* __restrict__ vals,
                                  const int*   __restrict__ rows,
                                  const int*   __restrict__ cols,
                                  unsigned* __restrict__ cursor,
                                  float2* __restrict__ records) {
    __shared__ unsigned cnt[NBINS];
    __shared__ unsigned base[NBINS];
    const int t = threadIdx.x;
    const long long chunk = (NNZ + gridDim.x - 1) / gridDim.x;
    const long long lo = (long long)blockIdx.x * chunk;
    const long long hi = (lo + chunk < NNZ) ? lo + chunk : NNZ;

    cnt[t] = 0;
    __syncthreads();
    for (long long i = lo + t; i < hi; i += blockDim.x)
        atomicAdd(&cnt[rows[i] >> BIN_SHIFT], 1u);
    __syncthreads();
    base[t] = atomicAdd(&cursor[t], cnt[t]);
    __syncthreads();
    cnt[t] = 0;
    __syncthreads();
    for (long long i = lo + t; i < hi; i += blockDim.x) {
        const int r = rows[i];
        const int bin = r >> BIN_SHIFT;
        const unsigned slot = atomicAdd(&cnt[bin], 1u);
        const unsigned pos = base[bin] + slot;
        const unsigned packed = ((unsigned)(r & (BIN_PX - 1)) << 19) | (unsigned)cols[i];
        records[pos] = make_float2(vals[i], __uint_as_float(packed));
    }
}

__global__ __launch_bounds__(256) void accum_kernel(
        const float2* __restrict__ records,
        const float*  __restrict__ sino_t,
        const unsigned* __restrict__ bin_start,
        float* __restrict__ acc) {
    __shared__ float lacc[BIN_PX * 6];   // 12 KB
    const int t = threadIdx.x;
    const int bin = blockIdx.x >> 2;     // / BPB
    const int bib = blockIdx.x & (BPB - 1);

    for (int j = t; j < BIN_PX * 6; j += blockDim.x) lacc[j] = 0.f;
    __syncthreads();

    const unsigned lo = bin_start[bin];
    const unsigned hi = bin_start[bin + 1];
    for (unsigned i = lo + bib * blockDim.x + t; i < hi; i += BPB * blockDim.x) {
        const float2 rec = records[i];
        const unsigned u = __float_as_uint(rec.y);
        const int col = (int)(u & 0x7FFFFu);
        const int lr  = (int)(u >> 19);
        const float* sp = sino_t + (size_t)col * 8;
        const float4 s0 = *(const float4*)sp;
        const float  s4 = sp[4];
        const float v = rec.x;
        float* b = lacc + lr * 6;
        atomicAdd(b + 0, v * s0.x);
        atomicAdd(b + 1, v * s0.y);
        atomicAdd(b + 2, v * s0.z);
        atomicAdd(b + 3, v * s0.w);
        atomicAdd(b + 4, v * s4);
        atomicAdd(b + 5, v);
    }
    __syncthreads();

    float* dst = acc + (size_t)bib * ACC_FLOATS + (size_t)bin * (BIN_PX * 6);
    for (int j = t; j < BIN_PX * 6; j += blockDim.x) dst[j] = lacc[j];
}

__global__ void reduce_divide_kernel(const float* __restrict__ acc,
                                     float* __restrict__ out) {
    const int p = blockIdx.x * blockDim.x + threadIdx.x;
    if (p < NPIX) {
        float n0 = 0.f, n1 = 0.f, n2 = 0.f, n3 = 0.f, n4 = 0.f, den = 0.f;
        for (int c = 0; c < BPB; ++c) {
            const float* b = acc + (size_t)c * ACC_FLOATS + (size_t)p * 6;
            n0 += b[0]; n1 += b[1]; n2 += b[2];
            n3 += b[3]; n4 += b[4]; den += b[5];
        }
        out[0 * (size_t)NPIX + p] = n0 / den;
        out[1 * (size_t)NPIX + p] = n1 / den;
        out[2 * (size_t)NPIX + p] = n2 / den;
        out[3 * (size_t)NPIX + p] = n3 / den;
        out[4 * (size_t)NPIX + p] = n4 / den;
    }
}

// ---------------- fallback kernels (small workspace) ----------------

__global__ void bp_scatter_fb_kernel(const float* __restrict__ sino,
                                     const float* __restrict__ vals,
                                     const int*   __restrict__ rows,
                                     const int*   __restrict__ cols,
                                     float* __restrict__ acc) {
    const long long stride = (long long)gridDim.x * blockDim.x;
    for (long long i = (long long)blockIdx.x * blockDim.x + threadIdx.x;
         i < NNZ; i += stride) {
        const float v = vals[i];
        const int   r = rows[i];
        const int   c = cols[i];
        atomicAdd(acc + (size_t)BSZ * NPIX + r, v);
#pragma unroll
        for (int b = 0; b < BSZ; ++b)
            atomicAdd(acc + (size_t)b * NPIX + r, v * sino[(size_t)b * SINO + c]);
    }
}

__global__ void bp_divide_fb_kernel(const float* __restrict__ acc,
                                    float* __restrict__ out) {
    const int i = blockIdx.x * blockDim.x + threadIdx.x;
    if (i < BSZ * NPIX) {
        const int p = i % NPIX;
        out[i] = acc[i] / acc[(size_t)BSZ * NPIX + p];
    }
}

// ---------------- launch ----------------

extern "C" void kernel_launch(void* const* d_in, const int* in_sizes, int n_in,
                              void* d_out, int out_size, void* d_ws, size_t ws_size,
                              hipStream_t stream) {
    const float* sino = (const float*)d_in[0];   // [BSZ, PROJ, DET, 1]
    const float* vals = (const float*)d_in[1];
    const int*   rows = (const int*)d_in[2];
    const int*   cols = (const int*)d_in[3];
    float* out = (float*)d_out;

    const int block = 256;

    // fast-path workspace layout (floats unless noted):
    //   records : NNZ float2                (160.0 MB)
    //   sino_t  : SINO*8                    ( 16.4 MB)
    //   acc     : BPB * ACC_FLOATS          ( 12.6 MB)
    //   meta    : hist[256] | bin_start[257] | cursor[256]  (u32)
    const size_t meta_u32 = NBINS + (NBINS + 1) + NBINS;
    const size_t need_fast =
        (REC_FLOATS + SINO_T_FLOATS + (size_t)BPB * ACC_FLOATS) * sizeof(float)
        + meta_u32 * sizeof(unsigned);

    if (ws_size >= need_fast) {
        float2*   records   = (float2*)d_ws;
        float*    sino_t    = (float*)d_ws + REC_FLOATS;
        float*    acc       = sino_t + SINO_T_FLOATS;
        unsigned* hist      = (unsigned*)(acc + (size_t)BPB * ACC_FLOATS);
        unsigned* bin_start = hist + NBINS;
        unsigned* cursor    = bin_start + (NBINS + 1);

        hipMemsetAsync(hist, 0, NBINS * sizeof(unsigned), stream);
        sino_transpose_kernel<<<(SINO + block - 1) / block, block, 0, stream>>>(sino, sino_t);
        hist_kernel<<<1024, NBINS, 0, stream>>>(rows, hist);
        scan_kernel<<<1, NBINS, 0, stream>>>(hist, bin_start, cursor);
        binscatter_kernel<<<2048, NBINS, 0, stream>>>(vals, rows, cols, cursor, records);
        accum_kernel<<<NBINS * BPB, block, 0, stream>>>(records, sino_t, bin_start, acc);
        reduce_divide_kernel<<<(NPIX + block - 1) / block, block, 0, stream>>>(acc, out);
    } else {
        // minimal-workspace fallback: device-scope scatter (slow but correct)
        float* acc = (float*)d_ws;  // (BSZ+1)*NPIX floats
        hipMemsetAsync(acc, 0, (size_t)(BSZ + 1) * NPIX * sizeof(float), stream);
        bp_scatter_fb_kernel<<<2048, block, 0, stream>>>(sino, vals, rows, cols, acc);
        const int n_out = BSZ * NPIX;
        bp_divide_fb_kernel<<<(n_out + block - 1) / block, block, 0, stream>>>(acc, out);
    }
}

// Round 5
// 875.354 us; speedup vs baseline: 6.8476x; 1.2042x over previous
//
#include <hip/hip_runtime.h>

#define BSZ  5
#define PROJ 1000
#define DET  513
#define IMG  362
#define NPIX (IMG * IMG)          // 131044
#define SINO (PROJ * DET)         // 513000
#define NNZ  20000000

#define NSHARD     4
#define SHARD_COLS (SINO / NSHARD)   // 128250
#define RB_SHIFT   10
#define RB_PX      1024
#define NRBIN      128               // ceil(NPIX/1024)
#define NBIN       (NRBIN * NSHARD)  // 512, bin = (row>>10)*4 + col/SHARD_COLS

#define SCAT_BLOCKS  256
#define SCAT_THREADS 1024
#define CHUNK        78128           // ceil(NNZ/256) rounded to mult of 16

#define ACC_THREADS  512
#define LSTRIDE      7               // odd stride -> conflict-free LDS atomics

// native clang vector types (HIP_vector_type not accepted by nontemporal builtins)
typedef int      i32x4 __attribute__((ext_vector_type(4)));
typedef float    f32x4 __attribute__((ext_vector_type(4)));
typedef float    f32x2 __attribute__((ext_vector_type(2)));
typedef unsigned u32x4 __attribute__((ext_vector_type(4)));

// ---------------- fast path kernels ----------------

// sino -> bf16 packed table: [col] = u32x4 {b0|b1<<16, b2|b3<<16, b4, 0}
__global__ void k_sino_bf16(const float* __restrict__ sino, u32x4* __restrict__ sino_b) {
    const int c = blockIdx.x * blockDim.x + threadIdx.x;
    if (c < SINO) {
        unsigned b[5];
#pragma unroll
        for (int k = 0; k < 5; ++k) {
            const unsigned u = __float_as_uint(sino[(size_t)k * SINO + c]);
            b[k] = (u + 0x7FFFu + ((u >> 16) & 1u)) >> 16;   // RNE to bf16
        }
        u32x4 o;
        o.x = b[0] | (b[1] << 16);
        o.y = b[2] | (b[3] << 16);
        o.z = b[4];
        o.w = 0u;
        sino_b[c] = o;
    }
}

__device__ __forceinline__ int bin_of(int row, int col) {
    return ((row >> RB_SHIFT) << 2) | (col / SHARD_COLS);
}

// pass A: per-(block,bin) exact counts (no global atomics)
__global__ __launch_bounds__(SCAT_THREADS) void k_count(
        const int* __restrict__ rows, const int* __restrict__ cols,
        unsigned* __restrict__ cnt) {
    __shared__ unsigned c[NBIN];
    const int t = threadIdx.x;
    for (int j = t; j < NBIN; j += SCAT_THREADS) c[j] = 0u;
    __syncthreads();
    const int lo = blockIdx.x * CHUNK;
    const int hi = (lo + CHUNK < NNZ) ? lo + CHUNK : NNZ;
    for (int i4 = lo / 4 + t; i4 * 4 < hi; i4 += SCAT_THREADS) {
        const i32x4 r = __builtin_nontemporal_load(((const i32x4*)rows) + i4);
        const i32x4 q = __builtin_nontemporal_load(((const i32x4*)cols) + i4);
        atomicAdd(&c[bin_of(r.x, q.x)], 1u);
        atomicAdd(&c[bin_of(r.y, q.y)], 1u);
        atomicAdd(&c[bin_of(r.z, q.z)], 1u);
        atomicAdd(&c[bin_of(r.w, q.w)], 1u);
    }
    __syncthreads();
    for (int j = t; j < NBIN; j += SCAT_THREADS)
        cnt[(size_t)blockIdx.x * NBIN + j] = c[j];
}

// per-bin totals: block b reduces cnt[*][b]
__global__ void k_tot(const unsigned* __restrict__ cnt, unsigned* __restrict__ tot) {
    __shared__ unsigned s[SCAT_BLOCKS];
    const int b = blockIdx.x, t = threadIdx.x;
    s[t] = cnt[(size_t)t * NBIN + b];
    __syncthreads();
    for (int o = SCAT_BLOCKS / 2; o > 0; o >>= 1) {
        if (t < o) s[t] += s[t + o];
        __syncthreads();
    }
    if (t == 0) tot[b] = s[0];
}

// exclusive scan of tot -> binoff (one block of NBIN threads)
__global__ void k_scan(const unsigned* __restrict__ tot, unsigned* __restrict__ binoff) {
    __shared__ unsigned s[NBIN];
    const int t = threadIdx.x;
    const unsigned my = tot[t];
    s[t] = my;
    __syncthreads();
    for (int o = 1; o < NBIN; o <<= 1) {
        const unsigned v = (t >= o) ? s[t - o] : 0u;
        __syncthreads();
        s[t] += v;
        __syncthreads();
    }
    binoff[t] = s[t] - my;
    if (t == NBIN - 1) binoff[NBIN] = (unsigned)NNZ;
}

// per-(block,bin) start positions: block b scans cnt[blk][b] over blk
__global__ void k_base(const unsigned* __restrict__ cnt,
                       const unsigned* __restrict__ binoff,
                       unsigned* __restrict__ base) {
    __shared__ unsigned s[SCAT_BLOCKS];
    const int b = blockIdx.x, t = threadIdx.x;
    const unsigned my = cnt[(size_t)t * NBIN + b];
    s[t] = my;
    __syncthreads();
    for (int o = 1; o < SCAT_BLOCKS; o <<= 1) {
        const unsigned v = (t >= o) ? s[t - o] : 0u;
        __syncthreads();
        s[t] += v;
        __syncthreads();
    }
    base[(size_t)t * NBIN + b] = binoff[b] + s[t] - my;
}

// pass B: scatter records {val, lr<<19|col} into bin-contiguous order
__global__ __launch_bounds__(SCAT_THREADS) void k_scatter(
        const float* __restrict__ vals, const int* __restrict__ rows,
        const int* __restrict__ cols, const unsigned* __restrict__ base,
        f32x2* __restrict__ rec) {
    __shared__ unsigned bs[NBIN];
    __shared__ unsigned c2[NBIN];
    const int t = threadIdx.x;
    for (int j = t; j < NBIN; j += SCAT_THREADS) {
        bs[j] = base[(size_t)blockIdx.x * NBIN + j];
        c2[j] = 0u;
    }
    __syncthreads();
    const int lo = blockIdx.x * CHUNK;
    const int hi = (lo + CHUNK < NNZ) ? lo + CHUNK : NNZ;
    for (int i4 = lo / 4 + t; i4 * 4 < hi; i4 += SCAT_THREADS) {
        const i32x4 r = __builtin_nontemporal_load(((const i32x4*)rows) + i4);
        const i32x4 q = __builtin_nontemporal_load(((const i32x4*)cols) + i4);
        const f32x4 v = __builtin_nontemporal_load(((const f32x4*)vals) + i4);
#define EMIT(RR, QQ, VV) do {                                            \
        const int bin = bin_of(RR, QQ);                                  \
        const unsigned slot = atomicAdd(&c2[bin], 1u);                   \
        const unsigned packed = ((unsigned)((RR) & (RB_PX - 1)) << 19) | (unsigned)(QQ); \
        f32x2 rc; rc.x = (VV); rc.y = __uint_as_float(packed);           \
        rec[bs[bin] + slot] = rc;                                        \
    } while (0)
        EMIT(r.x, q.x, v.x);
        EMIT(r.y, q.y, v.y);
        EMIT(r.z, q.z, v.z);
        EMIT(r.w, q.w, v.w);
#undef EMIT
    }
}

// accumulate one bin in LDS; blockIdx = bin = rbin*4 + shard (XCD-aligned shards)
__global__ __launch_bounds__(ACC_THREADS) void k_accum(
        const f32x2* __restrict__ rec, const u32x4* __restrict__ sino_b,
        const unsigned* __restrict__ binoff, float* __restrict__ acc) {
    __shared__ float l[RB_PX * LSTRIDE];   // 28 KB
    const int t = threadIdx.x;
    for (int j = t; j < RB_PX * LSTRIDE; j += ACC_THREADS) l[j] = 0.f;
    __syncthreads();
    const int bin = blockIdx.x;
    const unsigned lo = binoff[bin], hi = binoff[bin + 1];
    for (unsigned i = lo + t; i < hi; i += ACC_THREADS) {
        const f32x2 rc = __builtin_nontemporal_load(rec + i);
        const unsigned u = __float_as_uint(rc.y);
        const int col = (int)(u & 0x7FFFFu);
        const int lr  = (int)(u >> 19);
        const u32x4 sv = sino_b[col];
        const float v = rc.x;
        float* b = l + lr * LSTRIDE;
        atomicAdd(b + 0, v * __uint_as_float(sv.x << 16));
        atomicAdd(b + 1, v * __uint_as_float(sv.x & 0xFFFF0000u));
        atomicAdd(b + 2, v * __uint_as_float(sv.y << 16));
        atomicAdd(b + 3, v * __uint_as_float(sv.y & 0xFFFF0000u));
        atomicAdd(b + 4, v * __uint_as_float(sv.z << 16));
        atomicAdd(b + 5, v);
    }
    __syncthreads();
    float* dst = acc + (size_t)bin * (RB_PX * 6);
    for (int j = t; j < RB_PX * 6; j += ACC_THREADS)
        dst[j] = l[(j / 6) * LSTRIDE + (j % 6)];
}

// sum 4 shards per pixel, divide, write [BSZ][NPIX]
__global__ void k_reduce(const float* __restrict__ acc, float* __restrict__ out) {
    const int p = blockIdx.x * blockDim.x + threadIdx.x;
    if (p < NPIX) {
        const int rbin = p >> RB_SHIFT, lr = p & (RB_PX - 1);
        float n0 = 0.f, n1 = 0.f, n2 = 0.f, n3 = 0.f, n4 = 0.f, den = 0.f;
#pragma unroll
        for (int s = 0; s < NSHARD; ++s) {
            const float* b = acc + ((size_t)(rbin * NSHARD + s) * RB_PX + lr) * 6;
            n0 += b[0]; n1 += b[1]; n2 += b[2];
            n3 += b[3]; n4 += b[4]; den += b[5];
        }
        out[0 * (size_t)NPIX + p] = n0 / den;
        out[1 * (size_t)NPIX + p] = n1 / den;
        out[2 * (size_t)NPIX + p] = n2 / den;
        out[3 * (size_t)NPIX + p] = n3 / den;
        out[4 * (size_t)NPIX + p] = n4 / den;
    }
}

// ---------------- fallback kernels (small workspace) ----------------

__global__ void bp_scatter_fb_kernel(const float* __restrict__ sino,
                                     const float* __restrict__ vals,
                                     const int*   __restrict__ rows,
                                     const int*   __restrict__ cols,
                                     float* __restrict__ acc) {
    const long long stride = (long long)gridDim.x * blockDim.x;
    for (long long i = (long long)blockIdx.x * blockDim.x + threadIdx.x;
         i < NNZ; i += stride) {
        const float v = vals[i];
        const int   r = rows[i];
        const int   c = cols[i];
        atomicAdd(acc + (size_t)BSZ * NPIX + r, v);
#pragma unroll
        for (int b = 0; b < BSZ; ++b)
            atomicAdd(acc + (size_t)b * NPIX + r, v * sino[(size_t)b * SINO + c]);
    }
}

__global__ void bp_divide_fb_kernel(const float* __restrict__ acc,
                                    float* __restrict__ out) {
    const int i = blockIdx.x * blockDim.x + threadIdx.x;
    if (i < BSZ * NPIX) {
        const int p = i % NPIX;
        out[i] = acc[i] / acc[(size_t)BSZ * NPIX + p];
    }
}

// ---------------- launch ----------------

extern "C" void kernel_launch(void* const* d_in, const int* in_sizes, int n_in,
                              void* d_out, int out_size, void* d_ws, size_t ws_size,
                              hipStream_t stream) {
    const float* sino = (const float*)d_in[0];
    const float* vals = (const float*)d_in[1];
    const int*   rows = (const int*)d_in[2];
    const int*   cols = (const int*)d_in[3];
    float* out = (float*)d_out;

    // workspace layout (bytes, all 16B-aligned):
    //   rec    : NNZ * 8                  = 160,000,000
    //   sino_b : SINO * 16                =   8,208,000
    //   acc    : NBIN * RB_PX * 6 * 4     =  12,582,912
    //   cnt    : SCAT_BLOCKS * NBIN * 4   =     524,288
    //   base   : SCAT_BLOCKS * NBIN * 4   =     524,288
    //   tot    : NBIN * 4
    //   binoff : (NBIN+1) * 4
    const size_t rec_b    = (size_t)NNZ * 8;
    const size_t sino_b_b = (size_t)SINO * 16;
    const size_t acc_b    = (size_t)NBIN * RB_PX * 6 * 4;
    const size_t cnt_b    = (size_t)SCAT_BLOCKS * NBIN * 4;
    const size_t need = rec_b + sino_b_b + acc_b + 2 * cnt_b + (size_t)(NBIN + NBIN + 1 + 8) * 4;

    if (ws_size >= need) {
        char* w = (char*)d_ws;
        f32x2*    rec    = (f32x2*)w;                       w += rec_b;
        u32x4*    sinob  = (u32x4*)w;                       w += sino_b_b;
        float*    acc    = (float*)w;                       w += acc_b;
        unsigned* cnt    = (unsigned*)w;                    w += cnt_b;
        unsigned* base   = (unsigned*)w;                    w += cnt_b;
        unsigned* tot    = (unsigned*)w;                    w += (size_t)NBIN * 4;
        unsigned* binoff = (unsigned*)w;

        k_sino_bf16<<<(SINO + 255) / 256, 256, 0, stream>>>(sino, sinob);
        k_count<<<SCAT_BLOCKS, SCAT_THREADS, 0, stream>>>(rows, cols, cnt);
        k_tot<<<NBIN, SCAT_BLOCKS, 0, stream>>>(cnt, tot);
        k_scan<<<1, NBIN, 0, stream>>>(tot, binoff);
        k_base<<<NBIN, SCAT_BLOCKS, 0, stream>>>(cnt, binoff, base);
        k_scatter<<<SCAT_BLOCKS, SCAT_THREADS, 0, stream>>>(vals, rows, cols, base, rec);
        k_accum<<<NBIN, ACC_THREADS, 0, stream>>>(rec, sinob, binoff, acc);
        k_reduce<<<(NPIX + 255) / 256, 256, 0, stream>>>(acc, out);
    } else {
        float* acc = (float*)d_ws;
        (void)hipMemsetAsync(acc, 0, (size_t)(BSZ + 1) * NPIX * sizeof(float), stream);
        bp_scatter_fb_kernel<<<2048, 256, 0, stream>>>(sino, vals, rows, cols, acc);
        bp_divide_fb_kernel<<<(BSZ * NPIX + 255) / 256, 256, 0, stream>>>(acc, out);
    }
}